// Round 16
// baseline (295.265 us; speedup 1.0000x reference)
//
#include <hip/hip_runtime.h>
#include <hip/hip_bf16.h>

#define N_NODES 2048
#define N_EDGES 32768
#define BT      128           // B*T
#define TT      16
#define CH      32
#define E2      (N_EDGES + N_NODES)

static __device__ __forceinline__ unsigned pk2(float a, float b) {
    __hip_bfloat162 h2(__float2bfloat16(a), __float2bfloat16(b));   // a -> low 16
    return *reinterpret_cast<unsigned*>(&h2);
}

// ---------------- degree + attr segment sum ----------------
__global__ void deg_attr_kernel(const int* __restrict__ ei,
                                const float* __restrict__ ea,
                                int* __restrict__ deg, float* __restrict__ asum) {
    int e = blockIdx.x * 256 + threadIdx.x;
    if (e < N_EDGES) {
        int dst = ei[N_EDGES + e];
        atomicAdd(&deg[dst], 1);
        atomicAdd(&asum[dst], ea[e]);
    }
}

// ---------------- row_ptr scan (single wave) ----------------
__global__ void scan_kernel(const int* __restrict__ deg, int* __restrict__ rowp) {
    int lane = threadIdx.x;          // 64 threads
    int base = lane * 32;
    int loc[32];
    int s = 0;
    #pragma unroll
    for (int i = 0; i < 32; ++i) { loc[i] = s; s += deg[base + i] + 1; } // +1 self loop
    int inc = s;
    #pragma unroll
    for (int d = 1; d < 64; d <<= 1) {
        int v = __shfl_up(inc, d, 64);
        if (lane >= d) inc += v;
    }
    int excl = inc - s;
    #pragma unroll
    for (int i = 0; i < 32; ++i) rowp[base + i] = excl + loc[i];
    if (lane == 63) rowp[N_NODES] = inc;
}

// ---------------- scatter edges into CSR (by dst) ----------------
__global__ void scatter_kernel(const int* __restrict__ ei,
                               const float* __restrict__ ea,
                               const int* __restrict__ deg, const float* __restrict__ asum,
                               const int* __restrict__ rowp, int* __restrict__ fill,
                               int* __restrict__ col, float* __restrict__ attr_s) {
    int e = blockIdx.x * 256 + threadIdx.x;
    if (e >= E2) return;
    int src, dst; float a;
    if (e < N_EDGES) {
        src = ei[e]; dst = ei[N_EDGES + e]; a = ea[e];
    } else {
        int n = e - N_EDGES;
        src = n; dst = n;
        a = asum[n] / fmaxf((float)deg[n], 1.0f);   // mean edge attr
    }
    int pos = atomicAdd(&fill[dst], 1);
    col[rowp[dst] + pos]    = src;
    attr_s[rowp[dst] + pos] = a;
}

// ---------------- projection: xl AND xr -> packed bf16x2 rows [n][bt][16dw] ----------------
__global__ __launch_bounds__(256) void proj_kernel(
        const float* __restrict__ x,
        const float* __restrict__ Wl, const float* __restrict__ bl,
        const float* __restrict__ Wr, const float* __restrict__ br,
        unsigned* __restrict__ xlt, unsigned* __restrict__ xrt) {
    __shared__ float xs[128 * 32];     // [bt][f]
    __shared__ float wl[1024], wr[1024];
    int n = blockIdx.x;
    int tid = threadIdx.x;
    for (int i = tid; i < 1024; i += 256) { wl[i] = Wl[i]; wr[i] = Wr[i]; }
    #pragma unroll
    for (int i = 0; i < 16; ++i) {
        int e = i * 256 + tid;
        int bt = e >> 5, f = e & 31;
        xs[e] = x[((long)bt * N_NODES + n) * 32 + f];
    }
    __syncthreads();
    int c2  = tid & 15;
    int btl = tid >> 4;                // 0..15
    int c0 = 2 * c2, c1 = c0 + 1;
    float bl0 = bl[c0], bl1 = bl[c1];
    float br0 = br[c0], br1 = br[c1];
    for (int i = 0; i < 8; ++i) {
        int bt = i * 16 + btl;
        float a0 = 0.f, a1 = 0.f, r0 = 0.f, r1 = 0.f;
        #pragma unroll
        for (int f = 0; f < 32; ++f) {
            float xv = xs[bt * 32 + f];           // broadcast read
            a0 = fmaf(xv, wl[f * 32 + c0], a0);
            a1 = fmaf(xv, wl[f * 32 + c1], a1);
            r0 = fmaf(xv, wr[f * 32 + c0], r0);
            r1 = fmaf(xv, wr[f * 32 + c1], r1);
        }
        long o = ((long)n * 128 + bt) * 16 + c2;  // 64B row per (n,bt)
        xlt[o] = pk2(a0 + bl0, a1 + bl1);
        xrt[o] = pk2(r0 + br0, r1 + br1);
    }
}

// ---------------- GAT + x-side GRU gates fused; edge-parity waves + LDS merge ----------------
// Block = node. 4 waves = (btg, epar): wave covers 64 bt (lane=bt, full-coalesced 4KB/edge)
// and alternate CSR entries -> per-wave serial chain HALVES and wave count DOUBLES vs r10
// (4096->8192; r10-r15 showed gat is stall-bound on the per-edge dep chain, not bytes/VALU).
// Partial (den,acc) merged via LDS: own partial stays f32, peer half is bf16-rounded
// (~0.2% on h). Epilogue gates split by epar -> wih/bih indices WAVE-UNIFORM (s_load path;
// r13's divergent-index bug is what bloated VALU). xr precomputed (r14 win).
__global__ __launch_bounds__(256) void gat_kernel(
        const unsigned* __restrict__ xlt,   // [n][128][16] packed bf16x2 rows
        const unsigned* __restrict__ xrt,   // same layout
        const int* __restrict__ rowp, const int* __restrict__ col,
        const float* __restrict__ attr_s,
        const float* __restrict__ We, const float* __restrict__ att,
        const float* __restrict__ ob,
        const float* __restrict__ wih, const float* __restrict__ bih,
        __hip_bfloat16* __restrict__ gi) {   // [bt*N+n][96] bf16
    __shared__ unsigned accp[4][64][17];     // bf16x2-packed partial acc (pad 17: 2-way=free)
    __shared__ float    denp[4][64];
    int tid  = threadIdx.x;
    int wv   = tid >> 6;
    int lane = tid & 63;
    int btg  = wv >> 1;              // bt half (0: bt 0-63, 1: bt 64-127)
    int epar = wv & 1;               // edge parity
    int n    = blockIdx.x;
    int bt   = (btg << 6) | lane;

    long laneoff = (long)bt * 16;    // dword offset inside a node slab (2048 dwords)

    // xr row: one 64B load + unpack
    float xrv[32];
    {
        const uint4* rp = (const uint4*)(xrt + (long)n * 2048 + laneoff);
        uint4 A = rp[0], B = rp[1], C = rp[2], D = rp[3];
        unsigned u[16] = {A.x,A.y,A.z,A.w, B.x,B.y,B.z,B.w,
                          C.x,C.y,C.z,C.w, D.x,D.y,D.z,D.w};
        #pragma unroll
        for (int c2 = 0; c2 < 16; ++c2) {
            xrv[2*c2]   = __uint_as_float(u[c2] << 16);
            xrv[2*c2+1] = __uint_as_float(u[c2] & 0xffff0000u);
        }
    }

    float accv[32];
    #pragma unroll
    for (int c = 0; c < 32; ++c) accv[c] = 0.f;
    float den = 0.f;

    int beg = rowp[n], end = rowp[n + 1];    // deg >= 1 (self loop)
    for (int j = beg + epar; j < end; j += 2) {
        int   src = col[j];                  // wave-uniform -> s_load
        float av  = attr_s[j];
        const uint4* gp = (const uint4*)(xlt + (long)src * 2048 + laneoff);
        uint4 A = gp[0], B = gp[1], C = gp[2], D = gp[3];
        unsigned u[16] = {A.x,A.y,A.z,A.w, B.x,B.y,B.z,B.w,
                          C.x,C.y,C.z,C.w, D.x,D.y,D.z,D.w};

        float p0 = 0.f, p1 = 0.f, p2 = 0.f, p3 = 0.f;
        #pragma unroll
        for (int c2 = 0; c2 < 16; ++c2) {
            unsigned w2 = u[c2];
            float x0 = __uint_as_float(w2 << 16);
            float x1 = __uint_as_float(w2 & 0xffff0000u);
            int c = 2 * c2;
            float m0 = x0 + fmaf(av, We[c],     xrv[c]);     // We/att uniform -> SGPR
            float m1 = x1 + fmaf(av, We[c + 1], xrv[c + 1]);
            if (c2 & 1) { p2 = fmaf(att[c], fmaxf(m0, 0.2f * m0), p2);
                          p3 = fmaf(att[c + 1], fmaxf(m1, 0.2f * m1), p3); }
            else        { p0 = fmaf(att[c], fmaxf(m0, 0.2f * m0), p0);
                          p1 = fmaf(att[c + 1], fmaxf(m1, 0.2f * m1), p1); }
        }
        // scores bounded; softmax shift-invariant -> no max subtraction. Clamp = insurance.
        float p = fminf((p0 + p1) + (p2 + p3), 80.f);
        float w = __expf(p);
        den += w;
        #pragma unroll
        for (int c2 = 0; c2 < 16; ++c2) {
            unsigned w2 = u[c2];
            accv[2*c2]   = fmaf(w, __uint_as_float(w2 << 16),         accv[2*c2]);
            accv[2*c2+1] = fmaf(w, __uint_as_float(w2 & 0xffff0000u), accv[2*c2+1]);
        }
    }

    // exchange partials with the peer epar wave of the same btg
    #pragma unroll
    for (int k = 0; k < 16; ++k) accp[wv][lane][k] = pk2(accv[2*k], accv[2*k+1]);
    denp[wv][lane] = den;
    __syncthreads();
    int pw = wv ^ 1;
    den += denp[pw][lane];
    #pragma unroll
    for (int k = 0; k < 16; ++k) {
        unsigned u = accp[pw][lane][k];
        accv[2*k]   += __uint_as_float(u << 16);
        accv[2*k+1] += __uint_as_float(u & 0xffff0000u);
    }

    float inv = 1.f / den;
    #pragma unroll
    for (int c = 0; c < 32; ++c) accv[c] = fmaf(accv[c], inv, ob[c]);   // h

    // gi = h @ wih^T + bih for gates [epar*48, +48); indices wave-uniform -> s_load
    __hip_bfloat16* gip = gi + ((long)bt * N_NODES + n) * 96 + epar * 48;
    const float* wih_g = wih + epar * 48 * 32;
    const float* bih_g = bih + epar * 48;
    #pragma unroll
    for (int g8 = 0; g8 < 6; ++g8) {
        float s0 = bih_g[g8*8+0], s1 = bih_g[g8*8+1], s2 = bih_g[g8*8+2], s3 = bih_g[g8*8+3];
        float s4 = bih_g[g8*8+4], s5 = bih_g[g8*8+5], s6 = bih_g[g8*8+6], s7 = bih_g[g8*8+7];
        #pragma unroll
        for (int f = 0; f < 32; ++f) {
            float hf = accv[f];
            s0 = fmaf(hf, wih_g[(g8*8+0)*32+f], s0);
            s1 = fmaf(hf, wih_g[(g8*8+1)*32+f], s1);
            s2 = fmaf(hf, wih_g[(g8*8+2)*32+f], s2);
            s3 = fmaf(hf, wih_g[(g8*8+3)*32+f], s3);
            s4 = fmaf(hf, wih_g[(g8*8+4)*32+f], s4);
            s5 = fmaf(hf, wih_g[(g8*8+5)*32+f], s5);
            s6 = fmaf(hf, wih_g[(g8*8+6)*32+f], s6);
            s7 = fmaf(hf, wih_g[(g8*8+7)*32+f], s7);
        }
        uint4 v;
        v.x = pk2(s0, s1); v.y = pk2(s2, s3); v.z = pk2(s4, s5); v.w = pk2(s6, s7);
        *(uint4*)(gip + g8 * 8) = v;   // 8 bf16 = 16B store
    }
}

// ---------------- GRU recurrence: h-side only, 48 weights/lane, bf16 gi in ----------------
// one wave = one seq (b,n); lane = (c, fhalf): fhalf = lane>>5, c = lane&31.
__global__ __launch_bounds__(256) void gru_kernel(
        const float* __restrict__ whh, const float* __restrict__ bhh,
        const __hip_bfloat16* __restrict__ gi,   // [bt*N+n][96] bf16
        float* __restrict__ out) {               // [b,t,n,c]
    int tid  = threadIdx.x;
    int lane = tid & 63;
    int c    = lane & 31;
    int half = lane >> 5;
    int fbase = half << 4;
    int seq  = blockIdx.x * 4 + (tid >> 6);  // seq = b*2048 + n
    int b = seq >> 11;
    int n = seq & 2047;

    // 48 weights: rows {c, 32+c, 64+c} of whh, cols [fbase, fbase+16)
    float w0[16], w1[16], w2[16];
    #pragma unroll
    for (int k4 = 0; k4 < 4; ++k4) {
        float4 a0 = *(const float4*)&whh[( 0 + c) * 32 + fbase + k4 * 4];
        float4 a1 = *(const float4*)&whh[(32 + c) * 32 + fbase + k4 * 4];
        float4 a2 = *(const float4*)&whh[(64 + c) * 32 + fbase + k4 * 4];
        w0[k4*4+0]=a0.x; w0[k4*4+1]=a0.y; w0[k4*4+2]=a0.z; w0[k4*4+3]=a0.w;
        w1[k4*4+0]=a1.x; w1[k4*4+1]=a1.y; w1[k4*4+2]=a1.z; w1[k4*4+3]=a1.w;
        w2[k4*4+0]=a2.x; w2[k4*4+1]=a2.y; w2[k4*4+2]=a2.z; w2[k4*4+3]=a2.w;
    }
    float bh0 = half ? 0.f : bhh[c];        // count biases once (half0)
    float bh1 = half ? 0.f : bhh[32 + c];
    float bh2 = half ? 0.f : bhh[64 + c];

    const long GSTR = (long)N_NODES * 96;   // gi per-t stride
    long gbase = ((long)b * TT * N_NODES + n) * 96 + c;
    const long OSTR = (long)N_NODES * CH;
    long obase = ((long)b * TT * N_NODES + n) * CH + c;

    float hc = 0.f;
    float gr = __bfloat162float(gi[gbase]);
    float gz = __bfloat162float(gi[gbase + 32]);
    float gn = __bfloat162float(gi[gbase + 64]);
    #pragma unroll 1
    for (int t = 0; t < TT; ++t) {
        long gnx = gbase + (long)(t + 1) * GSTR;
        float grn = 0.f, gzn = 0.f, gnn = 0.f;
        if (t + 1 < TT) {
            grn = __bfloat162float(gi[gnx]);
            gzn = __bfloat162float(gi[gnx + 32]);
            gnn = __bfloat162float(gi[gnx + 64]);
        }
        float g0 = bh0, g1 = bh1, g2 = bh2;
        #pragma unroll
        for (int k = 0; k < 16; ++k) {
            float v = __shfl(hc, fbase + k, 64);   // h[f], sourced from half0 lanes
            g0 = fmaf(v, w0[k], g0);
            g1 = fmaf(v, w1[k], g1);
            g2 = fmaf(v, w2[k], g2);
        }
        float G0 = g0 + __shfl_xor(g0, 32, 64);    // hr + bhr  (full f-range)
        float G1 = g1 + __shfl_xor(g1, 32, 64);    // hz + bhz
        float G2 = g2 + __shfl_xor(g2, 32, 64);    // hn + bhn
        float r  = 1.f / (1.f + __expf(-(gr + G0)));
        float z  = 1.f / (1.f + __expf(-(gz + G1)));
        float a  = fmaf(r, G2, gn);
        float e2 = __expf(2.f * a);
        float nc = 1.f - 2.f / (e2 + 1.f);         // tanh, no inf/inf
        hc = (1.f - z) * nc + z * hc;
        if (half == 0) out[obase + (long)t * OSTR] = hc;   // coalesced 128B
        gr = grn; gz = gzn; gn = gnn;
    }
}

extern "C" void kernel_launch(void* const* d_in, const int* in_sizes, int n_in,
                              void* d_out, int out_size, void* d_ws, size_t ws_size,
                              hipStream_t stream) {
    const float* x    = (const float*)d_in[0];
    const int*   ei   = (const int*)d_in[1];
    const float* ea   = (const float*)d_in[2];
    const float* Wl   = (const float*)d_in[3];
    const float* bl   = (const float*)d_in[4];
    const float* Wr   = (const float*)d_in[5];
    const float* br   = (const float*)d_in[6];
    const float* We   = (const float*)d_in[7];
    const float* att  = (const float*)d_in[8];
    const float* ob   = (const float*)d_in[9];
    const float* wih  = (const float*)d_in[10];
    const float* whh  = (const float*)d_in[11];
    const float* bih  = (const float*)d_in[12];
    const float* bhh  = (const float*)d_in[13];
    float* out = (float*)d_out;

    // ---- workspace carve: small CSR metadata FIRST, then big arrays ----
    int*   deg  = (int*)d_ws;                  // N
    float* asum = (float*)(deg + N_NODES);     // N
    int*   fill = (int*)(asum + N_NODES);      // N
    int*   rowp = fill + N_NODES;              // N+1 (padded to +16)
    int*   col  = rowp + (N_NODES + 16);       // E2
    float* attr_s = (float*)(col + E2);        // E2
    unsigned* xlt = (unsigned*)(attr_s + E2);  // [N][128][16] packed = 16.8 MB
    xlt = (unsigned*)(((uintptr_t)xlt + 255) & ~(uintptr_t)255);
    unsigned* xrt = xlt + (long)N_NODES * 2048;                       // 16.8 MB
    __hip_bfloat16* gi = (__hip_bfloat16*)(xrt + (long)N_NODES * 2048);  // 50.3 MB

    // zero the three counter arrays (contiguous: deg, asum, fill)
    hipMemsetAsync(deg, 0, 3 * N_NODES * sizeof(int), stream);

    deg_attr_kernel<<<N_EDGES / 256, 256, 0, stream>>>(ei, ea, deg, asum);
    scan_kernel<<<1, 64, 0, stream>>>(deg, rowp);
    scatter_kernel<<<(E2 + 255) / 256, 256, 0, stream>>>(ei, ea, deg, asum, rowp, fill, col, attr_s);
    proj_kernel<<<N_NODES, 256, 0, stream>>>(x, Wl, bl, Wr, br, xlt, xrt);
    gat_kernel<<<N_NODES, 256, 0, stream>>>(xlt, xrt, rowp, col, attr_s,
                                            We, att, ob, wih, bih, gi);
    gru_kernel<<<(BT / TT * N_NODES) / 4, 256, 0, stream>>>(whh, bhh, gi, out);
}

// Round 17
// 250.977 us; speedup vs baseline: 1.1765x; 1.1765x over previous
//
#include <hip/hip_runtime.h>
#include <hip/hip_bf16.h>

#define N_NODES 2048
#define N_EDGES 32768
#define BT      128           // B*T
#define TT      16
#define CH      32
#define E2      (N_EDGES + N_NODES)

static __device__ __forceinline__ unsigned pk2(float a, float b) {
    __hip_bfloat162 h2(__float2bfloat16(a), __float2bfloat16(b));   // a -> low 16
    return *reinterpret_cast<unsigned*>(&h2);
}

// ---------------- degree + attr segment sum ----------------
__global__ void deg_attr_kernel(const int* __restrict__ ei,
                                const float* __restrict__ ea,
                                int* __restrict__ deg, float* __restrict__ asum) {
    int e = blockIdx.x * 256 + threadIdx.x;
    if (e < N_EDGES) {
        int dst = ei[N_EDGES + e];
        atomicAdd(&deg[dst], 1);
        atomicAdd(&asum[dst], ea[e]);
    }
}

// ---------------- row_ptr scan (single wave) ----------------
__global__ void scan_kernel(const int* __restrict__ deg, int* __restrict__ rowp) {
    int lane = threadIdx.x;          // 64 threads
    int base = lane * 32;
    int loc[32];
    int s = 0;
    #pragma unroll
    for (int i = 0; i < 32; ++i) { loc[i] = s; s += deg[base + i] + 1; } // +1 self loop
    int inc = s;
    #pragma unroll
    for (int d = 1; d < 64; d <<= 1) {
        int v = __shfl_up(inc, d, 64);
        if (lane >= d) inc += v;
    }
    int excl = inc - s;
    #pragma unroll
    for (int i = 0; i < 32; ++i) rowp[base + i] = excl + loc[i];
    if (lane == 63) rowp[N_NODES] = inc;
}

// ---------------- scatter edges into CSR (by dst) ----------------
__global__ void scatter_kernel(const int* __restrict__ ei,
                               const float* __restrict__ ea,
                               const int* __restrict__ deg, const float* __restrict__ asum,
                               const int* __restrict__ rowp, int* __restrict__ fill,
                               int* __restrict__ col, float* __restrict__ attr_s) {
    int e = blockIdx.x * 256 + threadIdx.x;
    if (e >= E2) return;
    int src, dst; float a;
    if (e < N_EDGES) {
        src = ei[e]; dst = ei[N_EDGES + e]; a = ea[e];
    } else {
        int n = e - N_EDGES;
        src = n; dst = n;
        a = asum[n] / fmaxf((float)deg[n], 1.0f);   // mean edge attr
    }
    int pos = atomicAdd(&fill[dst], 1);
    col[rowp[dst] + pos]    = src;
    attr_s[rowp[dst] + pos] = a;
}

// ---------------- projection: xl AND xr -> packed bf16x2, column layout [n][16][128] ----------------
__global__ __launch_bounds__(256) void proj_kernel(
        const float* __restrict__ x,
        const float* __restrict__ Wl, const float* __restrict__ bl,
        const float* __restrict__ Wr, const float* __restrict__ br,
        unsigned* __restrict__ xlt, unsigned* __restrict__ xrt) {
    __shared__ float xs[128 * 32];     // [bt][f]
    __shared__ float wl[1024], wr[1024];
    int n = blockIdx.x;
    int tid = threadIdx.x;
    for (int i = tid; i < 1024; i += 256) { wl[i] = Wl[i]; wr[i] = Wr[i]; }
    #pragma unroll
    for (int i = 0; i < 16; ++i) {
        int e = i * 256 + tid;
        int bt = e >> 5, f = e & 31;
        xs[e] = x[((long)bt * N_NODES + n) * 32 + f];
    }
    __syncthreads();
    int c2  = tid & 15;
    int btl = tid >> 4;                // 0..15
    int c0 = 2 * c2, c1 = c0 + 1;
    float bl0 = bl[c0], bl1 = bl[c1];
    float br0 = br[c0], br1 = br[c1];
    for (int i = 0; i < 8; ++i) {
        int bt = i * 16 + btl;
        float a0 = 0.f, a1 = 0.f, r0 = 0.f, r1 = 0.f;
        #pragma unroll
        for (int f = 0; f < 32; ++f) {
            float xv = xs[bt * 32 + f];           // broadcast read
            a0 = fmaf(xv, wl[f * 32 + c0], a0);
            a1 = fmaf(xv, wl[f * 32 + c1], a1);
            r0 = fmaf(xv, wr[f * 32 + c0], r0);
            r1 = fmaf(xv, wr[f * 32 + c1], r1);
        }
        long o = (long)n * 2048 + c2 * 128 + bt;  // [n][c2][bt]
        xlt[o] = pk2(a0 + bl0, a1 + bl1);
        xrt[o] = pk2(r0 + br0, r1 + br1);
    }
}

// ---------------- GAT + x-side GRU gates fused (r10/r11 proven structure) ----------------
// lane = bt; one wave = (node, 64 bt). Edge loop IDENTICAL to r10/r11 (the only shape
// that hit 125us; r12-r16 restructures all regressed). Two grafts only:
// (1) xr prologue reads PACKED xrt (16 coalesced dwords, 256B/instr) instead of 32 f32
//     at 256KB lane-stride (~2048 L2 transactions/wave) -- r14's validated win.
// (2) gi stored [n][bt][96]: per-wave stores = one 12KB contiguous block, and gru's
//     per-t stride drops 393KB -> 192B (line-neighbor reads).
__global__ __launch_bounds__(256) void gat_kernel(
        const unsigned* __restrict__ xlt,   // [n][16][128] packed bf16x2
        const unsigned* __restrict__ xrt,   // same layout
        const int* __restrict__ rowp, const int* __restrict__ col,
        const float* __restrict__ attr_s,
        const float* __restrict__ We, const float* __restrict__ att,
        const float* __restrict__ ob,
        const float* __restrict__ wih, const float* __restrict__ bih,
        __hip_bfloat16* __restrict__ gi) {   // [n][bt][96] bf16
    int tid = threadIdx.x;
    int wv = tid >> 6, lane = tid & 63;
    int task = blockIdx.x * 4 + wv;      // 4096 tasks = 2048 n x 2 btg
    int n   = task >> 1;
    int bt  = ((task & 1) << 6) | lane;

    // xr row: 16 coalesced dwords + unpack (graft 1)
    float xrv[32];
    {
        const unsigned* rp = xrt + (long)n * 2048 + bt;
        #pragma unroll
        for (int c2 = 0; c2 < 16; ++c2) {
            unsigned u = rp[c2 * 128];
            xrv[2*c2]   = __uint_as_float(u << 16);
            xrv[2*c2+1] = __uint_as_float(u & 0xffff0000u);
        }
    }

    float accv[32];
    #pragma unroll
    for (int c = 0; c < 32; ++c) accv[c] = 0.f;

    int beg = rowp[n];
    int end = rowp[n + 1];           // deg >= 1 always (self loop)
    float den = 0.f;
    const unsigned* xbase = xlt + bt;
    for (int j = beg; j < end; ++j) {
        int   src = col[j];
        float av  = attr_s[j];
        const unsigned* gp = xbase + (long)src * 2048;
        unsigned u[16];
        #pragma unroll
        for (int c2 = 0; c2 < 16; ++c2) u[c2] = gp[c2 * 128];

        float p0 = 0.f, p1 = 0.f, p2 = 0.f, p3 = 0.f;
        #pragma unroll
        for (int c2 = 0; c2 < 16; ++c2) {
            unsigned w2 = u[c2];
            float x0 = __uint_as_float(w2 << 16);
            float x1 = __uint_as_float(w2 & 0xffff0000u);
            int c = 2 * c2;
            float m0 = x0 + fmaf(av, We[c],     xrv[c]);
            float m1 = x1 + fmaf(av, We[c + 1], xrv[c + 1]);
            if (c2 & 1) { p2 = fmaf(att[c], fmaxf(m0, 0.2f * m0), p2);
                          p3 = fmaf(att[c + 1], fmaxf(m1, 0.2f * m1), p3); }
            else        { p0 = fmaf(att[c], fmaxf(m0, 0.2f * m0), p0);
                          p1 = fmaf(att[c + 1], fmaxf(m1, 0.2f * m1), p1); }
        }
        // scores bounded; softmax shift-invariant -> no max subtraction. Clamp = insurance.
        float p = fminf((p0 + p1) + (p2 + p3), 80.f);
        float w = __expf(p);
        den += w;
        #pragma unroll
        for (int c2 = 0; c2 < 16; ++c2) {
            unsigned w2 = u[c2];
            accv[2*c2]   = fmaf(w, __uint_as_float(w2 << 16),         accv[2*c2]);
            accv[2*c2+1] = fmaf(w, __uint_as_float(w2 & 0xffff0000u), accv[2*c2+1]);
        }
    }
    float inv = 1.f / den;
    #pragma unroll
    for (int c = 0; c < 32; ++c) accv[c] = fmaf(accv[c], inv, ob[c]);   // h

    // gi = h @ wih^T + bih ; wih reads wave-uniform -> s_load; 8 chains per 16B store
    __hip_bfloat16* gip = gi + ((long)n * 128 + bt) * 96;   // graft 2: [n][bt][96]
    #pragma unroll
    for (int g8 = 0; g8 < 12; ++g8) {
        float s0 = bih[g8*8+0], s1 = bih[g8*8+1], s2 = bih[g8*8+2], s3 = bih[g8*8+3];
        float s4 = bih[g8*8+4], s5 = bih[g8*8+5], s6 = bih[g8*8+6], s7 = bih[g8*8+7];
        #pragma unroll
        for (int f = 0; f < 32; ++f) {
            float hf = accv[f];
            s0 = fmaf(hf, wih[(g8*8+0)*32+f], s0);
            s1 = fmaf(hf, wih[(g8*8+1)*32+f], s1);
            s2 = fmaf(hf, wih[(g8*8+2)*32+f], s2);
            s3 = fmaf(hf, wih[(g8*8+3)*32+f], s3);
            s4 = fmaf(hf, wih[(g8*8+4)*32+f], s4);
            s5 = fmaf(hf, wih[(g8*8+5)*32+f], s5);
            s6 = fmaf(hf, wih[(g8*8+6)*32+f], s6);
            s7 = fmaf(hf, wih[(g8*8+7)*32+f], s7);
        }
        uint4 v;
        v.x = pk2(s0, s1); v.y = pk2(s2, s3); v.z = pk2(s4, s5); v.w = pk2(s6, s7);
        *(uint4*)(gip + g8 * 8) = v;   // 8 bf16 = 16B store
    }
}

// ---------------- GRU recurrence: h-side only, 48 weights/lane, bf16 gi in ----------------
// one wave = one seq (b,n); lane = (c, fhalf). gi now [n][bt][96] with bt = b*16+t:
// per-t read stride is 192B (was 393KB) -> near-sequential L1/L2-resident reads.
__global__ __launch_bounds__(256) void gru_kernel(
        const float* __restrict__ whh, const float* __restrict__ bhh,
        const __hip_bfloat16* __restrict__ gi,   // [n][bt][96] bf16
        float* __restrict__ out) {               // [b,t,n,c]
    int tid  = threadIdx.x;
    int lane = tid & 63;
    int c    = lane & 31;
    int half = lane >> 5;
    int fbase = half << 4;
    int seq  = blockIdx.x * 4 + (tid >> 6);  // seq = b*2048 + n
    int b = seq >> 11;
    int n = seq & 2047;

    // 48 weights: rows {c, 32+c, 64+c} of whh, cols [fbase, fbase+16)
    float w0[16], w1[16], w2[16];
    #pragma unroll
    for (int k4 = 0; k4 < 4; ++k4) {
        float4 a0 = *(const float4*)&whh[( 0 + c) * 32 + fbase + k4 * 4];
        float4 a1 = *(const float4*)&whh[(32 + c) * 32 + fbase + k4 * 4];
        float4 a2 = *(const float4*)&whh[(64 + c) * 32 + fbase + k4 * 4];
        w0[k4*4+0]=a0.x; w0[k4*4+1]=a0.y; w0[k4*4+2]=a0.z; w0[k4*4+3]=a0.w;
        w1[k4*4+0]=a1.x; w1[k4*4+1]=a1.y; w1[k4*4+2]=a1.z; w1[k4*4+3]=a1.w;
        w2[k4*4+0]=a2.x; w2[k4*4+1]=a2.y; w2[k4*4+2]=a2.z; w2[k4*4+3]=a2.w;
    }
    float bh0 = half ? 0.f : bhh[c];        // count biases once (half0)
    float bh1 = half ? 0.f : bhh[32 + c];
    float bh2 = half ? 0.f : bhh[64 + c];

    long gbase = ((long)n * 128 + b * TT) * 96 + c;   // [n][bt][96], bt = b*16+t
    const long OSTR = (long)N_NODES * CH;
    long obase = ((long)b * TT * N_NODES + n) * CH + c;

    float hc = 0.f;
    float gr = __bfloat162float(gi[gbase]);
    float gz = __bfloat162float(gi[gbase + 32]);
    float gn = __bfloat162float(gi[gbase + 64]);
    #pragma unroll 1
    for (int t = 0; t < TT; ++t) {
        long gnx = gbase + (long)(t + 1) * 96;
        float grn = 0.f, gzn = 0.f, gnn = 0.f;
        if (t + 1 < TT) {
            grn = __bfloat162float(gi[gnx]);
            gzn = __bfloat162float(gi[gnx + 32]);
            gnn = __bfloat162float(gi[gnx + 64]);
        }
        float g0 = bh0, g1 = bh1, g2 = bh2;
        #pragma unroll
        for (int k = 0; k < 16; ++k) {
            float v = __shfl(hc, fbase + k, 64);   // h[f], sourced from half0 lanes
            g0 = fmaf(v, w0[k], g0);
            g1 = fmaf(v, w1[k], g1);
            g2 = fmaf(v, w2[k], g2);
        }
        float G0 = g0 + __shfl_xor(g0, 32, 64);    // hr + bhr  (full f-range)
        float G1 = g1 + __shfl_xor(g1, 32, 64);    // hz + bhz
        float G2 = g2 + __shfl_xor(g2, 32, 64);    // hn + bhn
        float r  = 1.f / (1.f + __expf(-(gr + G0)));
        float z  = 1.f / (1.f + __expf(-(gz + G1)));
        float a  = fmaf(r, G2, gn);
        float e2 = __expf(2.f * a);
        float nc = 1.f - 2.f / (e2 + 1.f);         // tanh, no inf/inf
        hc = (1.f - z) * nc + z * hc;
        if (half == 0) out[obase + (long)t * OSTR] = hc;   // coalesced 128B
        gr = grn; gz = gzn; gn = gnn;
    }
}

extern "C" void kernel_launch(void* const* d_in, const int* in_sizes, int n_in,
                              void* d_out, int out_size, void* d_ws, size_t ws_size,
                              hipStream_t stream) {
    const float* x    = (const float*)d_in[0];
    const int*   ei   = (const int*)d_in[1];
    const float* ea   = (const float*)d_in[2];
    const float* Wl   = (const float*)d_in[3];
    const float* bl   = (const float*)d_in[4];
    const float* Wr   = (const float*)d_in[5];
    const float* br   = (const float*)d_in[6];
    const float* We   = (const float*)d_in[7];
    const float* att  = (const float*)d_in[8];
    const float* ob   = (const float*)d_in[9];
    const float* wih  = (const float*)d_in[10];
    const float* whh  = (const float*)d_in[11];
    const float* bih  = (const float*)d_in[12];
    const float* bhh  = (const float*)d_in[13];
    float* out = (float*)d_out;

    // ---- workspace carve: small CSR metadata FIRST, then big arrays ----
    int*   deg  = (int*)d_ws;                  // N
    float* asum = (float*)(deg + N_NODES);     // N
    int*   fill = (int*)(asum + N_NODES);      // N
    int*   rowp = fill + N_NODES;              // N+1 (padded to +16)
    int*   col  = rowp + (N_NODES + 16);       // E2
    float* attr_s = (float*)(col + E2);        // E2
    unsigned* xlt = (unsigned*)(attr_s + E2);  // [N][16][128] packed = 16.8 MB
    xlt = (unsigned*)(((uintptr_t)xlt + 255) & ~(uintptr_t)255);
    unsigned* xrt = xlt + (long)N_NODES * 2048;                       // 16.8 MB
    __hip_bfloat16* gi = (__hip_bfloat16*)(xrt + (long)N_NODES * 2048);  // 50.3 MB

    // zero the three counter arrays (contiguous: deg, asum, fill)
    hipMemsetAsync(deg, 0, 3 * N_NODES * sizeof(int), stream);

    deg_attr_kernel<<<N_EDGES / 256, 256, 0, stream>>>(ei, ea, deg, asum);
    scan_kernel<<<1, 64, 0, stream>>>(deg, rowp);
    scatter_kernel<<<(E2 + 255) / 256, 256, 0, stream>>>(ei, ea, deg, asum, rowp, fill, col, attr_s);
    proj_kernel<<<N_NODES, 256, 0, stream>>>(x, Wl, bl, Wr, br, xlt, xrt);
    gat_kernel<<<(N_NODES * 2) / 4, 256, 0, stream>>>(xlt, xrt, rowp, col, attr_s,
                                                      We, att, ob, wih, bih, gi);
    gru_kernel<<<(BT / TT * N_NODES) / 4, 256, 0, stream>>>(whh, bhh, gi, out);
}